// Round 13
// baseline (1776.050 us; speedup 1.0000x reference)
//
#include <hip/hip_runtime.h>
#include <hip/hip_bf16.h>

#define BATCH 2048
#define LSIG 2048
#define TSTEPS 512
#define CH 16
#define NCHUNK (TSTEPS / CH)

typedef float v2f __attribute__((ext_vector_type(2)));
typedef float v4f __attribute__((ext_vector_type(4)));
typedef __bf16 b16x8 __attribute__((ext_vector_type(8)));
typedef float f32x4 __attribute__((ext_vector_type(4)));

#define PKFMA(d, a, b) asm("v_pk_fma_f32 %0, %1, %2, %0" : "+v"(d) : "v"(a), "v"(b))

__device__ __forceinline__ float sigf(float x) {
    return __fdividef(1.f, 1.f + __expf(-x));
}
__device__ __forceinline__ float tanhfast(float x) {
    return 1.f - __fdividef(2.f, __expf(2.f * x) + 1.f);
}
__device__ __forceinline__ unsigned short bf16rne(float f) {
    unsigned u = __float_as_uint(f);
    return (unsigned short)((u + 0x7FFFu + ((u >> 16) & 1u)) >> 16);
}
// swizzled channel position: K2 lane q reads 16B-contiguous frag halves
__device__ __forceinline__ int swz(int co) {
    return (co < 16) ? ((co >> 2) * 8 + (co & 3))
                     : (((co >> 2) - 4) * 8 + 4 + (co & 3));
}

// ============ K1: conv front-end for ONE chunk -> seq hi/lo planes =========
__global__ __launch_bounds__(64) void frontend_kernel(
    const float* __restrict__ x0, const float* __restrict__ x1,
    const float* __restrict__ x2, const float* __restrict__ x3,
    const float* __restrict__ c1w, const float* __restrict__ c1b,
    const float* __restrict__ c2w, const float* __restrict__ c2b,
    unsigned short* __restrict__ seqh, unsigned short* __restrict__ seql,
    int t0, int Tseg)
{
    const int s    = blockIdx.x;
    const int br   = blockIdx.y & 3;
    const int ck   = blockIdx.y >> 2;
    const int lane = threadIdx.x;
    const float* xg = (br == 0) ? x0 : (br == 1) ? x1 : (br == 2) ? x2 : x3;

    __shared__ float xs_c[70];
    __shared__ float p1buf[34][16];

    const int ci = lane & 15;
    const int co = lane & 31;
    const int hf = lane >> 5;
    const int sp = swz(co);
    const int tc0 = t0 + ck * CH;
    const int lt0 = ck * CH;

    const float w10 = c1w[br * 48 + ci * 3 + 0];
    const float w11 = c1w[br * 48 + ci * 3 + 1];
    const float w12 = c1w[br * 48 + ci * 3 + 2];
    const float b1v = c1b[br * 16 + ci];

    float wt[24];
    {
        const v4f* p = (const v4f*)(c2w + br * 1536 + co * 48 + hf * 24);
        #pragma unroll
        for (int i = 0; i < 6; ++i) ((v4f*)wt)[i] = p[i];
    }
    v4f w2p[3][2];
    #pragma unroll
    for (int k = 0; k < 3; ++k)
        #pragma unroll
        for (int h2 = 0; h2 < 2; ++h2)
            w2p[k][h2] = (v4f){ wt[(h2 * 4 + 0) * 3 + k], wt[(h2 * 4 + 1) * 3 + k],
                                wt[(h2 * 4 + 2) * 3 + k], wt[(h2 * 4 + 3) * 3 + k] };
    const float b2v = c2b[br * 32 + co];

    {
        int g = 4 * tc0 - 3 + lane;
        xs_c[lane] = ((unsigned)g < (unsigned)LSIG) ? xg[(size_t)s * LSIG + g] : 0.f;
        if (lane < 6) {
            int g2 = 4 * tc0 + 61 + lane;
            xs_c[64 + lane] = ((unsigned)g2 < (unsigned)LSIG) ? xg[(size_t)s * LSIG + g2] : 0.f;
        }
    }
    __syncthreads();

    #pragma unroll 1
    for (int it = 0; it < 9; ++it) {
        int idx = it * 64 + lane;
        if (idx < 34 * 16) {
            int pl = idx >> 4;
            float xa = xs_c[2 * pl + 0], xb = xs_c[2 * pl + 1];
            float xc = xs_c[2 * pl + 2], xd = xs_c[2 * pl + 3];
            float a0 = fmaf(xc, w12, fmaf(xb, w11, fmaf(xa, w10, b1v)));
            float a1 = fmaf(xd, w12, fmaf(xc, w11, fmaf(xb, w10, b1v)));
            float v = fmaxf(fmaxf(a0, a1), 0.f);
            int p1g = 2 * tc0 - 1 + pl;
            v = ((unsigned)p1g < (unsigned)(LSIG / 2)) ? v : 0.f;
            p1buf[pl][idx & 15] = v;
        }
    }
    __syncthreads();

    {
        const v4f* pbase = (const v4f*)&p1buf[0][0];
        const int h2o = hf * 2;
        v4f r0a = pbase[0 * 4 + h2o], r0b = pbase[0 * 4 + h2o + 1];
        v4f r1a = pbase[1 * 4 + h2o], r1b = pbase[1 * 4 + h2o + 1];
        v4f r2a = pbase[2 * 4 + h2o], r2b = pbase[2 * 4 + h2o + 1];
        v4f r3a = pbase[3 * 4 + h2o], r3b = pbase[3 * 4 + h2o + 1];
        #pragma unroll 1
        for (int tl = 0; tl < CH; ++tl) {
            v2f aA = {0.f, 0.f}, aB = {0.f, 0.f};
            PKFMA(aA, r0a.xy, w2p[0][0].xy); PKFMA(aA, r0a.zw, w2p[0][0].zw);
            PKFMA(aA, r0b.xy, w2p[0][1].xy); PKFMA(aA, r0b.zw, w2p[0][1].zw);
            PKFMA(aA, r1a.xy, w2p[1][0].xy); PKFMA(aA, r1a.zw, w2p[1][0].zw);
            PKFMA(aA, r1b.xy, w2p[1][1].xy); PKFMA(aA, r1b.zw, w2p[1][1].zw);
            PKFMA(aA, r2a.xy, w2p[2][0].xy); PKFMA(aA, r2a.zw, w2p[2][0].zw);
            PKFMA(aA, r2b.xy, w2p[2][1].xy); PKFMA(aA, r2b.zw, w2p[2][1].zw);
            PKFMA(aB, r1a.xy, w2p[0][0].xy); PKFMA(aB, r1a.zw, w2p[0][0].zw);
            PKFMA(aB, r1b.xy, w2p[0][1].xy); PKFMA(aB, r1b.zw, w2p[0][1].zw);
            PKFMA(aB, r2a.xy, w2p[1][0].xy); PKFMA(aB, r2a.zw, w2p[1][0].zw);
            PKFMA(aB, r2b.xy, w2p[1][1].xy); PKFMA(aB, r2b.zw, w2p[1][1].zw);
            PKFMA(aB, r3a.xy, w2p[2][0].xy); PKFMA(aB, r3a.zw, w2p[2][0].zw);
            PKFMA(aB, r3b.xy, w2p[2][1].xy); PKFMA(aB, r3b.zw, w2p[2][1].zw);
            float sA = aA.x + aA.y, sB = aB.x + aB.y;
            sA += __shfl_xor(sA, 32);
            sB += __shfl_xor(sB, 32);
            float sv = fmaxf(fmaxf(sA, sB) + b2v, 0.f);
            unsigned short hb = bf16rne(sv);
            float hif = __uint_as_float(((unsigned)hb) << 16);
            unsigned short lb = bf16rne(sv - hif);
            size_t off = (((size_t)br * Tseg + (lt0 + tl)) * 2048 + s) * 32 + sp;
            if (hf == 0) seqh[off] = hb;
            else         seql[off] = lb;
            r0a = r2a; r0b = r2b; r1a = r3a; r1b = r3b;
            if (tl < CH - 1) {
                r2a = pbase[(2 * tl + 4) * 4 + h2o]; r2b = pbase[(2 * tl + 4) * 4 + h2o + 1];
                r3a = pbase[(2 * tl + 5) * 4 + h2o]; r3b = pbase[(2 * tl + 5) * 4 + h2o + 1];
            }
        }
    }
}

// ============ K2: MFMA LSTM, 16 samples/group, 2 waves/group ==============
// wave0: n=0..3 (i,f tiles); wave1: n=4..7 (g,o). 24 MFMAs/wave/step.
// Exchange post-activation gate values via parity LDS (1 barrier/step);
// both waves redundantly update c,h and repack the h B-frag.
// x-part MFMAs software-pipelined: xacc(t+1) computed at end of step t.
__global__ __launch_bounds__(128, 1) void lstm_mfma_kernel(
    const unsigned short* __restrict__ seqh, const unsigned short* __restrict__ seql,
    const float* __restrict__ wih, const float* __restrict__ whh,
    const float* __restrict__ bih, const float* __restrict__ bhh,
    float* __restrict__ state, float* __restrict__ feats,
    int t0, int Tseg)
{
    const int s0   = blockIdx.x * 16;
    const int br   = blockIdx.y;
    const int tid  = threadIdx.x;
    const int w    = tid >> 6;
    const int lane = tid & 63;
    const int c    = lane & 15;
    const int q    = lane >> 4;

    __shared__ f32x4 ex[2][2][4][64];   // [parity][wave][m][lane] — b128-coalesced

    // weights + bias for this wave's 4 n-tiles (n = 4*w + m)
    b16x8 wihhi[4], wihlo[4], whhhi[4], whhlo[4];
    f32x4 bias[4];
    #pragma unroll
    for (int m = 0; m < 4; ++m) {
        const int n = 4 * w + m;
        const int gr = 16 * n + c;
        const float* pi = wih + (size_t)br * 4096 + (size_t)gr * 32;
        const float* ph = whh + (size_t)br * 4096 + (size_t)gr * 32;
        v4f ia = *(const v4f*)(pi + 4 * q);
        v4f ib = *(const v4f*)(pi + 16 + 4 * q);
        v4f ha = *(const v4f*)(ph + 4 * q);
        v4f hb = *(const v4f*)(ph + 16 + 4 * q);
        #pragma unroll
        for (int j = 0; j < 4; ++j) {
            __bf16 tt;
            tt = (__bf16)ia[j]; wihhi[m][j]     = tt; wihlo[m][j]     = (__bf16)(ia[j] - (float)tt);
            tt = (__bf16)ib[j]; wihhi[m][4 + j] = tt; wihlo[m][4 + j] = (__bf16)(ib[j] - (float)tt);
            tt = (__bf16)ha[j]; whhhi[m][j]     = tt; whhlo[m][j]     = (__bf16)(ha[j] - (float)tt);
            tt = (__bf16)hb[j]; whhhi[m][4 + j] = tt; whhlo[m][4 + j] = (__bf16)(hb[j] - (float)tt);
        }
        #pragma unroll
        for (int r = 0; r < 4; ++r) {
            int g = 16 * n + 4 * q + r;
            bias[m][r] = bih[br * 128 + g] + bhh[br * 128 + g];
        }
    }

    // state (both waves hold identical copies)
    b16x8 bhh_f, bhl_f;
    float cst[2][4];
    if (t0 == 0) {
        #pragma unroll
        for (int j = 0; j < 8; ++j) { bhh_f[j] = (__bf16)0.f; bhl_f[j] = (__bf16)0.f; }
        #pragma unroll
        for (int hh = 0; hh < 2; ++hh)
            #pragma unroll
            for (int r = 0; r < 4; ++r) cst[hh][r] = 0.f;
    } else {
        const float* st = state + (((size_t)br * BATCH + s0 + c) * 2) * 32;
        #pragma unroll
        for (int hh = 0; hh < 2; ++hh)
            #pragma unroll
            for (int r = 0; r < 4; ++r) {
                int u = 16 * hh + 4 * q + r;
                float hv = st[u];
                __bf16 hb2 = (__bf16)hv;
                bhh_f[hh * 4 + r] = hb2;
                bhl_f[hh * 4 + r] = (__bf16)(hv - (float)hb2);
                cst[hh][r] = st[32 + u];
            }
    }

    // prologue: x(0) + xacc
    f32x4 xacc[4];
    {
        size_t rowe = (((size_t)br * Tseg + 0) * 2048 + s0 + c) * 32 + (size_t)q * 8;
        b16x8 bxh = *reinterpret_cast<const b16x8*>(seqh + rowe);
        b16x8 bxl = *reinterpret_cast<const b16x8*>(seql + rowe);
        #pragma unroll
        for (int m = 0; m < 4; ++m) {
            xacc[m] = __builtin_amdgcn_mfma_f32_16x16x32_bf16(wihhi[m], bxh, bias[m], 0, 0, 0);
            xacc[m] = __builtin_amdgcn_mfma_f32_16x16x32_bf16(wihhi[m], bxl, xacc[m], 0, 0, 0);
            xacc[m] = __builtin_amdgcn_mfma_f32_16x16x32_bf16(wihlo[m], bxh, xacc[m], 0, 0, 0);
        }
    }

    #pragma unroll 1
    for (int t = 0; t < Tseg; ++t) {
        // issue next-x loads early (consumed at end of step)
        b16x8 nxh, nxl;
        const bool more = (t < Tseg - 1);
        if (more) {
            size_t re = (((size_t)br * Tseg + (t + 1)) * 2048 + s0 + c) * 32 + (size_t)q * 8;
            nxh = *reinterpret_cast<const b16x8*>(seqh + re);
            nxl = *reinterpret_cast<const b16x8*>(seql + re);
        }

        // h-part: 3 chained MFMAs per m, starting from pipelined xacc
        f32x4 acc[4];
        #pragma unroll
        for (int m = 0; m < 4; ++m) {
            acc[m] = __builtin_amdgcn_mfma_f32_16x16x32_bf16(whhhi[m], bhh_f, xacc[m], 0, 0, 0);
            acc[m] = __builtin_amdgcn_mfma_f32_16x16x32_bf16(whhhi[m], bhl_f, acc[m], 0, 0, 0);
            acc[m] = __builtin_amdgcn_mfma_f32_16x16x32_bf16(whhlo[m], bhh_f, acc[m], 0, 0, 0);
        }

        // own-gate activation: wave0 -> sigmoid(i,f); wave1 -> tanh(g), sig(o)
        f32x4 a[4];
        if (w == 0) {
            #pragma unroll
            for (int m = 0; m < 4; ++m)
                #pragma unroll
                for (int r = 0; r < 4; ++r) a[m][r] = sigf(acc[m][r]);
        } else {
            #pragma unroll
            for (int m = 0; m < 2; ++m)
                #pragma unroll
                for (int r = 0; r < 4; ++r) a[m][r] = tanhfast(acc[m][r]);
            #pragma unroll
            for (int m = 2; m < 4; ++m)
                #pragma unroll
                for (int r = 0; r < 4; ++r) a[m][r] = sigf(acc[m][r]);
        }

        // exchange (parity buffers -> single barrier per step)
        const int par = t & 1;
        #pragma unroll
        for (int m = 0; m < 4; ++m) ex[par][w][m][lane] = a[m];
        __syncthreads();
        f32x4 ob[4];
        #pragma unroll
        for (int m = 0; m < 4; ++m) ob[m] = ex[par][w ^ 1][m][lane];

        // cell update (redundant in both waves; P = i,f values; Q = g,o values)
        const bool last = (t0 + t == TSTEPS - 1);
        const f32x4* P = (w == 0) ? a : ob;
        const f32x4* Q = (w == 0) ? ob : a;
        #pragma unroll
        for (int hh = 0; hh < 2; ++hh) {
            #pragma unroll
            for (int r = 0; r < 4; ++r) {
                float vi = P[hh][r], vf = P[2 + hh][r];
                float vg = Q[hh][r], vo = Q[2 + hh][r];
                float cc = fmaf(vf, cst[hh][r], vi * vg);
                cst[hh][r] = cc;
                float hv = vo * tanhfast(cc);
                __bf16 hb2 = (__bf16)hv;
                bhh_f[hh * 4 + r] = hb2;
                bhl_f[hh * 4 + r] = (__bf16)(hv - (float)hb2);
                if (last && w == 0)
                    feats[((size_t)br * BATCH + s0 + c) * 32 + 16 * hh + 4 * q + r] = hv;
            }
        }

        // xacc for step t+1 (off the h-critical-path)
        if (more) {
            #pragma unroll
            for (int m = 0; m < 4; ++m) {
                xacc[m] = __builtin_amdgcn_mfma_f32_16x16x32_bf16(wihhi[m], nxh, bias[m], 0, 0, 0);
                xacc[m] = __builtin_amdgcn_mfma_f32_16x16x32_bf16(wihhi[m], nxl, xacc[m], 0, 0, 0);
                xacc[m] = __builtin_amdgcn_mfma_f32_16x16x32_bf16(wihlo[m], nxh, xacc[m], 0, 0, 0);
            }
        }
    }

    // save state for next segment (wave0 only)
    if (w == 0 && t0 + Tseg < TSTEPS) {
        float* st = state + (((size_t)br * BATCH + s0 + c) * 2) * 32;
        #pragma unroll
        for (int hh = 0; hh < 2; ++hh)
            #pragma unroll
            for (int r = 0; r < 4; ++r) {
                int u = 16 * hh + 4 * q + r;
                st[u]      = (float)bhh_f[hh * 4 + r] + (float)bhl_f[hh * 4 + r];
                st[32 + u] = cst[hh][r];
            }
    }
}

// ============ fallback: R7 monolithic branch kernel ========================
__global__ __launch_bounds__(64, 2) void branch_fallback(
    const float* __restrict__ x0, const float* __restrict__ x1,
    const float* __restrict__ x2, const float* __restrict__ x3,
    const float* __restrict__ c1w, const float* __restrict__ c1b,
    const float* __restrict__ c2w, const float* __restrict__ c2b,
    const float* __restrict__ wih, const float* __restrict__ whh,
    const float* __restrict__ bih, const float* __restrict__ bhh,
    float* __restrict__ feats)
{
    const int s    = blockIdx.x;
    const int br   = blockIdx.y;
    const int lane = threadIdx.x;
    const float* xg = (br == 0) ? x0 : (br == 1) ? x1 : (br == 2) ? x2 : x3;

    __shared__ float xs_c[70];
    __shared__ float p1buf[34][16];
    __shared__ float seqb[CH][32];
    __shared__ float hb[2][32];

    const int ci = lane & 15;
    const int co = lane & 31;
    const int hf = lane >> 5;

    const float bs0 = bih[br * 128 + lane]      + bhh[br * 128 + lane];
    const float bs1 = bih[br * 128 + lane + 64] + bhh[br * 128 + lane + 64];

    if (lane < 32) hb[0][lane] = 0.f;
    float c_state = 0.f;

    #pragma unroll 1
    for (int chk = 0; chk < NCHUNK; ++chk) {
        const int tc0 = chk * CH;
        {
            int g = 4 * tc0 - 3 + lane;
            xs_c[lane] = ((unsigned)g < (unsigned)LSIG) ? xg[(size_t)s * LSIG + g] : 0.f;
            if (lane < 6) {
                int g2 = 4 * tc0 + 61 + lane;
                xs_c[64 + lane] = ((unsigned)g2 < (unsigned)LSIG) ? xg[(size_t)s * LSIG + g2] : 0.f;
            }
        }
        const float* pc1 = c1w + br * 48 + ci * 3;  asm volatile("" : "+v"(pc1));
        const float w10 = pc1[0], w11 = pc1[1], w12 = pc1[2];
        const float* pb1 = c1b + br * 16 + ci;      asm volatile("" : "+v"(pb1));
        const float b1v = pb1[0];
        const float* pc2 = c2w + br * 1536 + co * 48 + hf * 24;
        asm volatile("" : "+v"(pc2));
        float wt[24];
        #pragma unroll
        for (int i = 0; i < 6; ++i) ((v4f*)wt)[i] = ((const v4f*)pc2)[i];
        v4f w2p[3][2];
        #pragma unroll
        for (int k = 0; k < 3; ++k)
            #pragma unroll
            for (int h2 = 0; h2 < 2; ++h2)
                w2p[k][h2] = (v4f){ wt[(h2 * 4 + 0) * 3 + k], wt[(h2 * 4 + 1) * 3 + k],
                                    wt[(h2 * 4 + 2) * 3 + k], wt[(h2 * 4 + 3) * 3 + k] };
        const float* pb2 = c2b + br * 32 + co;      asm volatile("" : "+v"(pb2));
        const float b2v = pb2[0];
        __syncthreads();
        #pragma unroll 1
        for (int it = 0; it < 9; ++it) {
            int idx = it * 64 + lane;
            if (idx < 34 * 16) {
                int pl = idx >> 4;
                float xa = xs_c[2 * pl + 0], xb = xs_c[2 * pl + 1];
                float xc = xs_c[2 * pl + 2], xd = xs_c[2 * pl + 3];
                float a0 = fmaf(xc, w12, fmaf(xb, w11, fmaf(xa, w10, b1v)));
                float a1 = fmaf(xd, w12, fmaf(xc, w11, fmaf(xb, w10, b1v)));
                float v = fmaxf(fmaxf(a0, a1), 0.f);
                int p1g = 2 * tc0 - 1 + pl;
                v = ((unsigned)p1g < (unsigned)(LSIG / 2)) ? v : 0.f;
                p1buf[pl][idx & 15] = v;
            }
        }
        __syncthreads();
        {
            const v4f* pbase = (const v4f*)&p1buf[0][0];
            const int h2o = hf * 2;
            v4f r0a = pbase[0 * 4 + h2o], r0b = pbase[0 * 4 + h2o + 1];
            v4f r1a = pbase[1 * 4 + h2o], r1b = pbase[1 * 4 + h2o + 1];
            v4f r2a = pbase[2 * 4 + h2o], r2b = pbase[2 * 4 + h2o + 1];
            v4f r3a = pbase[3 * 4 + h2o], r3b = pbase[3 * 4 + h2o + 1];
            #pragma unroll 1
            for (int tl = 0; tl < CH; ++tl) {
                v2f aA = {0.f, 0.f}, aB = {0.f, 0.f};
                PKFMA(aA, r0a.xy, w2p[0][0].xy); PKFMA(aA, r0a.zw, w2p[0][0].zw);
                PKFMA(aA, r0b.xy, w2p[0][1].xy); PKFMA(aA, r0b.zw, w2p[0][1].zw);
                PKFMA(aA, r1a.xy, w2p[1][0].xy); PKFMA(aA, r1a.zw, w2p[1][0].zw);
                PKFMA(aA, r1b.xy, w2p[1][1].xy); PKFMA(aA, r1b.zw, w2p[1][1].zw);
                PKFMA(aA, r2a.xy, w2p[2][0].xy); PKFMA(aA, r2a.zw, w2p[2][0].zw);
                PKFMA(aA, r2b.xy, w2p[2][1].xy); PKFMA(aA, r2b.zw, w2p[2][1].zw);
                PKFMA(aB, r1a.xy, w2p[0][0].xy); PKFMA(aB, r1a.zw, w2p[0][0].zw);
                PKFMA(aB, r1b.xy, w2p[0][1].xy); PKFMA(aB, r1b.zw, w2p[0][1].zw);
                PKFMA(aB, r2a.xy, w2p[1][0].xy); PKFMA(aB, r2a.zw, w2p[1][0].zw);
                PKFMA(aB, r2b.xy, w2p[1][1].xy); PKFMA(aB, r2b.zw, w2p[1][1].zw);
                PKFMA(aB, r3a.xy, w2p[2][0].xy); PKFMA(aB, r3a.zw, w2p[2][0].zw);
                PKFMA(aB, r3b.xy, w2p[2][1].xy); PKFMA(aB, r3b.zw, w2p[2][1].zw);
                float sA = aA.x + aA.y, sB = aB.x + aB.y;
                sA += __shfl_xor(sA, 32);
                sB += __shfl_xor(sB, 32);
                if (hf == 0)
                    seqb[tl][co] = fmaxf(fmaxf(sA, sB) + b2v, 0.f);
                r0a = r2a; r0b = r2b; r1a = r3a; r1b = r3b;
                if (tl < CH - 1) {
                    r2a = pbase[(2 * tl + 4) * 4 + h2o]; r2b = pbase[(2 * tl + 4) * 4 + h2o + 1];
                    r3a = pbase[(2 * tl + 5) * 4 + h2o]; r3b = pbase[(2 * tl + 5) * 4 + h2o + 1];
                }
            }
        }
        __syncthreads();
        float gpx0[CH], gpx1[CH];
        {
            const float* pwi = wih + (size_t)br * 4096 + (size_t)lane * 32;
            asm volatile("" : "+v"(pwi));
            v4f wiA[8], wiB[8];
            #pragma unroll
            for (int j = 0; j < 8; ++j) {
                wiA[j] = ((const v4f*)pwi)[j];
                wiB[j] = ((const v4f*)(pwi + 64 * 32))[j];
            }
            #pragma unroll
            for (int tl = 0; tl < CH; ++tl) {
                const v4f* xq = (const v4f*)&seqb[tl][0];
                v2f aA = {0.f, 0.f}, aB = {0.f, 0.f};
                #pragma unroll
                for (int j = 0; j < 8; ++j) {
                    v4f xv = xq[j];
                    PKFMA(aA, xv.xy, wiA[j].xy); PKFMA(aA, xv.zw, wiA[j].zw);
                    PKFMA(aB, xv.xy, wiB[j].xy); PKFMA(aB, xv.zw, wiB[j].zw);
                }
                gpx0[tl] = aA.x + aA.y;
                gpx1[tl] = aB.x + aB.y;
            }
        }
        {
            const float* pwh = whh + (size_t)br * 4096 + (size_t)lane * 32;
            asm volatile("" : "+v"(pwh));
            v4f whA[8], whB[8];
            #pragma unroll
            for (int j = 0; j < 8; ++j) {
                whA[j] = ((const v4f*)pwh)[j];
                whB[j] = ((const v4f*)(pwh + 64 * 32))[j];
            }
            #pragma unroll
            for (int tl = 0; tl < CH; ++tl) {
                __syncthreads();
                const int p = (tc0 + tl) & 1;
                const v4f* hq = (const v4f*)&hb[p][0];
                v2f aA = {0.f, 0.f}, aB = {0.f, 0.f};
                #pragma unroll
                for (int j = 0; j < 8; ++j) {
                    v4f hv = hq[j];
                    PKFMA(aA, hv.xy, whA[j].xy); PKFMA(aA, hv.zw, whA[j].zw);
                    PKFMA(aB, hv.xy, whB[j].xy); PKFMA(aB, hv.zw, whB[j].zw);
                }
                float g0 = bs0 + gpx0[tl] + aA.x + aA.y;
                float g1 = bs1 + gpx1[tl] + aB.x + aB.y;
                float a0 = sigf(g0);
                float earg = (lane < 32) ? 2.f * g1 : -g1;
                float e1 = __expf(fminf(earg, 80.f));
                float num = (lane < 32) ? e1 - 1.f : 1.f;
                float a1 = __fdividef(num, e1 + 1.f);
                float fa = __shfl_xor(a0, 32);
                float oa = __shfl_xor(a1, 32);
                if (lane < 32) {
                    c_state = fmaf(fa, c_state, a0 * a1);
                    hb[p ^ 1][lane] = oa * tanhfast(c_state);
                }
            }
        }
    }
    __syncthreads();
    if (lane < 32)
        feats[((size_t)br * BATCH + s) * 32 + lane] = hb[0][lane];
}

// ---------------- tail: bottleneck + 8-qubit statevector + classifier -------

__device__ __forceinline__ void apply1q(float2* psi, int lane, int q,
                                        float2 g00, float2 g01,
                                        float2 g10, float2 g11)
{
    const int shift = 7 - q;
    const int right = 1 << shift;
    #pragma unroll
    for (int pp = 0; pp < 2; ++pp) {
        int p  = lane + 64 * pp;
        int l  = p >> shift;
        int r  = p & (right - 1);
        int i0 = (l << (shift + 1)) + r;
        int i1 = i0 + right;
        float2 a = psi[i0], b = psi[i1];
        float2 n0 = make_float2(g00.x * a.x - g00.y * a.y + g01.x * b.x - g01.y * b.y,
                                g00.x * a.y + g00.y * a.x + g01.x * b.y + g01.y * b.x);
        float2 n1 = make_float2(g10.x * a.x - g10.y * a.y + g11.x * b.x - g11.y * b.y,
                                g10.x * a.y + g10.y * a.x + g11.x * b.y + g11.y * b.x);
        psi[i0] = n0;
        psi[i1] = n1;
    }
    __syncthreads();
}

__global__ __launch_bounds__(64) void tail_kernel(
    const float* __restrict__ feats, const float* __restrict__ bw,
    const float* __restrict__ bb, const float* __restrict__ qw,
    const float* __restrict__ cw, const float* __restrict__ cb,
    float* __restrict__ out)
{
    const int s    = blockIdx.x;
    const int lane = threadIdx.x;

    __shared__ float comb[128];
    __shared__ float2 psi[256];
    __shared__ float ang[8];

    comb[lane]      = feats[(size_t)(lane >> 5) * (BATCH * 32) + (size_t)s * 32 + (lane & 31)];
    comb[lane + 64] = feats[(size_t)((lane + 64) >> 5) * (BATCH * 32) + (size_t)s * 32 + (lane & 31)];
    __syncthreads();

    {
        int q = lane >> 3, k0 = lane & 7;
        float p = 0.f;
        #pragma unroll
        for (int i = 0; i < 16; ++i) {
            int k = k0 + 8 * i;
            p = fmaf(comb[k], bw[q * 128 + k], p);
        }
        p += __shfl_xor(p, 4);
        p += __shfl_xor(p, 2);
        p += __shfl_xor(p, 1);
        if (k0 == 0) ang[q] = tanhf(p + bb[q]);
    }
    #pragma unroll
    for (int r = 0; r < 4; ++r) {
        int idx = lane + 64 * r;
        psi[idx] = make_float2(idx == 0 ? 1.f : 0.f, 0.f);
    }
    __syncthreads();

    const float PI_F = 3.14159265358979323846f;

    for (int q = 0; q < 8; ++q) {
        float half = ang[q] * PI_F * 0.5f;
        float cv = cosf(half), sv = sinf(half);
        apply1q(psi, lane, q,
                make_float2(cv, 0.f), make_float2(0.f, -sv),
                make_float2(0.f, -sv), make_float2(cv, 0.f));
    }

    for (int l = 0; l < 3; ++l) {
        for (int q = 0; q < 8; ++q) {
            float phi = qw[(l * 8 + q) * 3 + 0];
            float th  = qw[(l * 8 + q) * 3 + 1];
            float om  = qw[(l * 8 + q) * 3 + 2];
            float ct = cosf(0.5f * th), st = sinf(0.5f * th);
            float A = 0.5f * (phi + om), D = 0.5f * (phi - om);
            float cA = cosf(A), sA = sinf(A), cD = cosf(D), sD = sinf(D);
            apply1q(psi, lane, q,
                    make_float2(ct * cA, -ct * sA), make_float2(-st * cD, -st * sD),
                    make_float2(st * cD, -st * sD), make_float2(ct * cA,  ct * sA));
        }
        int stride = l + 1;
        for (int q = 0; q + stride < 8; ++q) {
            int cbit = 1 << (7 - q);
            int tbit = 1 << (7 - (q + stride));
            #pragma unroll
            for (int r = 0; r < 4; ++r) {
                int idx = lane + 64 * r;
                if ((idx & cbit) && !(idx & tbit)) {
                    int j = idx | tbit;
                    float2 tmp = psi[idx];
                    psi[idx] = psi[j];
                    psi[j] = tmp;
                }
            }
            __syncthreads();
        }
    }

    float z[8];
    #pragma unroll
    for (int q = 0; q < 8; ++q) z[q] = 0.f;
    #pragma unroll
    for (int r = 0; r < 4; ++r) {
        int idx = lane + 64 * r;
        float2 a = psi[idx];
        float pr = a.x * a.x + a.y * a.y;
        #pragma unroll
        for (int q = 0; q < 8; ++q)
            z[q] += (idx & (1 << (7 - q))) ? -pr : pr;
    }
    #pragma unroll
    for (int q = 0; q < 8; ++q) {
        #pragma unroll
        for (int off = 32; off; off >>= 1) z[q] += __shfl_xor(z[q], off);
    }
    if (lane == 0) {
        #pragma unroll
        for (int c = 0; c < 3; ++c) {
            float acc = cb[c];
            #pragma unroll
            for (int q = 0; q < 8; ++q) acc = fmaf(z[q], cw[c * 8 + q], acc);
            out[s * 3 + c] = acc;
        }
    }
}

extern "C" void kernel_launch(void* const* d_in, const int* in_sizes, int n_in,
                              void* d_out, int out_size, void* d_ws, size_t ws_size,
                              hipStream_t stream)
{
    (void)in_sizes; (void)n_in; (void)out_size;
    const float* x0  = (const float*)d_in[0];
    const float* x1  = (const float*)d_in[1];
    const float* x2  = (const float*)d_in[2];
    const float* x3  = (const float*)d_in[3];
    const float* c1w = (const float*)d_in[4];
    const float* c1b = (const float*)d_in[5];
    const float* c2w = (const float*)d_in[6];
    const float* c2b = (const float*)d_in[7];
    const float* wih = (const float*)d_in[8];
    const float* whh = (const float*)d_in[9];
    const float* bih = (const float*)d_in[10];
    const float* bhh = (const float*)d_in[11];
    const float* bw  = (const float*)d_in[12];
    const float* bb  = (const float*)d_in[13];
    const float* qw  = (const float*)d_in[14];
    const float* cw  = (const float*)d_in[15];
    const float* cb  = (const float*)d_in[16];

    const size_t state_b = 4ULL * BATCH * 64ULL * 4ULL;       // 2 MB
    const size_t feats_b = 4ULL * BATCH * 32ULL * 4ULL;       // 1 MB
    const size_t per_t   = 4ULL * 2048ULL * 32ULL * 4ULL;     // 1 MB/step (hi+lo)

    int Tseg = 0;
    for (int cand = 512; cand >= 32; cand >>= 1) {
        if ((size_t)cand * per_t + state_b + feats_b <= ws_size) { Tseg = cand; break; }
    }

    if (Tseg > 0) {
        size_t seg_elems = (size_t)Tseg * 4ULL * 2048ULL * 32ULL;
        unsigned short* seqh = (unsigned short*)d_ws;
        unsigned short* seql = seqh + seg_elems;
        float* state = (float*)((char*)d_ws + 2ULL * seg_elems * 2ULL);
        float* feats = (float*)((char*)state + state_b);

        for (int t0 = 0; t0 < TSTEPS; t0 += Tseg) {
            frontend_kernel<<<dim3(BATCH, 4 * (Tseg / CH)), 64, 0, stream>>>(
                x0, x1, x2, x3, c1w, c1b, c2w, c2b, seqh, seql, t0, Tseg);
            lstm_mfma_kernel<<<dim3(BATCH / 16, 4), 128, 0, stream>>>(
                seqh, seql, wih, whh, bih, bhh, state, feats, t0, Tseg);
        }
        tail_kernel<<<BATCH, 64, 0, stream>>>(
            feats, bw, bb, qw, cw, cb, (float*)d_out);
    } else {
        float* feats = (float*)d_ws;
        branch_fallback<<<dim3(BATCH, 4), 64, 0, stream>>>(
            x0, x1, x2, x3, c1w, c1b, c2w, c2b, wih, whh, bih, bhh, feats);
        tail_kernel<<<BATCH, 64, 0, stream>>>(
            feats, bw, bb, qw, cw, cb, (float*)d_out);
    }
}